// Round 2
// baseline (200.984 us; speedup 1.0000x reference)
//
#include <hip/hip_runtime.h>
#include <math.h>

#define D_IN 512          // feature dim
#define ROWS_PER_WAVE 32  // rows per wave = 64 lanes / 2 reuse samples

// ---------- complex helpers ----------
struct c2 { float x, y; };
__device__ __forceinline__ c2 cmul(c2 a, c2 b) { return {a.x*b.x - a.y*b.y, a.x*b.y + a.y*b.x}; }

// Packed butterfly merge: lanes with (lane&o)==0 end with (a + a_partner),
// lanes with (lane&o)!=0 end with (b + b_partner). One shuffle merges two values.
__device__ __forceinline__ float pack2(float a, float b, int o, int lane) {
    float v = (lane & o) ? b : a;
    float u = (lane & o) ? a : b;
    return v + __shfl_xor(u, o, 64);
}

// =====================================================================
// Fully fused: GEMV8 (wave-per-row) + 4-qubit circuit + reuse-mean + head.
// Wave w owns rows [32w, 32w+32). After the row loop, lane 2r+u holds the
// 4 features of sample (row 32w+r, reuse u); all 64 lanes then run one
// circuit each.
// =====================================================================
__global__ __launch_bounds__(256, 2)
void bqc_fused_kernel(const float* __restrict__ x,     // [B][512]
                      const float* __restrict__ W,     // [8][512]
                      const float* __restrict__ bias,  // [8]
                      const float* __restrict__ qp,    // [12]
                      const float* __restrict__ Wc,    // [2][4]
                      const float* __restrict__ bc,    // [2]
                      float* __restrict__ out,         // [B][2]
                      int B)
{
    const int lane = threadIdx.x & 63;
    const int wid  = blockIdx.x * (blockDim.x >> 6) + (threadIdx.x >> 6);
    const int base = wid * ROWS_PER_WAVE;
    if (base >= B) return;

    // ---- register-resident W slice: W[j][8*lane .. 8*lane+8) ----
    float4 w0[8], w1[8];
    #pragma unroll
    for (int j = 0; j < 8; ++j) {
        const float4* wp = (const float4*)(W + j * D_IN + lane * 8);
        w0[j] = wp[0]; w1[j] = wp[1];
    }

    // ---- trainable unitaries V_i = RZ(c) RY(b) RX(a), composed once ----
    c2 V[4][4];   // [qubit][00,01,10,11]
    #pragma unroll
    for (int i = 0; i < 4; ++i) {
        float sa, ca, sb, cb, sc, cc;
        sincosf(qp[3*i]   * 0.5f, &sa, &ca);   // RX half-angle
        sincosf(qp[3*i+1] * 0.5f, &sb, &cb);   // RY half-angle
        sincosf(qp[3*i+2] * 0.5f, &sc, &cc);   // RZ half-angle
        // M = RY(b) @ RX(a):  RX = [[(ca,0),(0,-sa)],[(0,-sa),(ca,0)]]
        c2 M00 = {  cb*ca,  sb*sa };
        c2 M01 = { -sb*ca, -cb*sa };
        c2 M10 = {  sb*ca, -cb*sa };
        c2 M11 = {  cb*ca, -sb*sa };
        // V = diag(e^{-ic/2}, e^{+ic/2}) @ M
        c2 e0 = { cc, -sc }, e1 = { cc, sc };
        V[i][0] = cmul(e0, M00); V[i][1] = cmul(e0, M01);
        V[i][2] = cmul(e1, M10); V[i][3] = cmul(e1, M11);
    }

    const int u = lane & 1;                       // reuse index of this lane
    const int gbase = (lane & 56) | (u << 2);     // shfl source base (value replicas)

    float f[4] = {0.f, 0.f, 0.f, 0.f};            // this lane's sample features

    // ---- row loop with depth-1 prefetch ----
    const float* xl = x + lane * 8;
    {
        const int r0 = min(base, B - 1);
        const float4* xp = (const float4*)(xl + (size_t)r0 * D_IN);
        float4 cx0 = xp[0], cx1 = xp[1];

        for (int rr = 0; rr < ROWS_PER_WAVE; ++rr) {
            const int nrow = min(base + rr + 1, B - 1);
            const float4* np = (const float4*)(xl + (size_t)nrow * D_IN);
            float4 nx0 = np[0], nx1 = np[1];

            float acc[8];
            #pragma unroll
            for (int j = 0; j < 8; ++j) {
                acc[j] = cx0.x*w0[j].x + cx0.y*w0[j].y + cx0.z*w0[j].z + cx0.w*w0[j].w
                       + cx1.x*w1[j].x + cx1.y*w1[j].y + cx1.z*w1[j].z + cx1.w*w1[j].w;
            }
            // packed reduction: 7 merge shuffles + 3 plain butterflies
            float p0 = pack2(acc[0], acc[1], 1, lane);
            float p1 = pack2(acc[2], acc[3], 1, lane);
            float p2 = pack2(acc[4], acc[5], 1, lane);
            float p3 = pack2(acc[6], acc[7], 1, lane);
            float q0 = pack2(p0, p1, 2, lane);
            float q1 = pack2(p2, p3, 2, lane);
            float r  = pack2(q0, q1, 4, lane);
            r += __shfl_xor(r,  8, 64);
            r += __shfl_xor(r, 16, 64);
            r += __shfl_xor(r, 32, 64);
            // now lane l holds S_{l&7} (full dot for output l&7 of this row)

            // deposit row rr's features into lane pair (2rr, 2rr+1)
            float g0 = __shfl(r, gbase + 0, 64);
            float g1 = __shfl(r, gbase + 1, 64);
            float g2 = __shfl(r, gbase + 2, 64);
            float g3 = __shfl(r, gbase + 3, 64);
            const bool mine = ((lane >> 1) == rr);
            f[0] = mine ? g0 : f[0];
            f[1] = mine ? g1 : f[1];
            f[2] = mine ? g2 : f[2];
            f[3] = mine ? g3 : f[3];

            cx0 = nx0; cx1 = nx1;
        }
    }
    // add bias for this lane's reuse half
    #pragma unroll
    for (int j = 0; j < 4; ++j) f[j] += bias[4*u + j];

    // ---- 4-qubit circuit, one sample per lane ----
    float ar[16], ai[16];
    #pragma unroll
    for (int k = 0; k < 16; ++k) { ar[k] = 0.25f; ai[k] = 0.f; }  // H^4 |0000>

    #pragma unroll
    for (int i = 0; i < 4; ++i) {
        float sf, cf;
        sincosf(f[i] * 1.57079632679489662f, &sf, &cf);  // RY(feat*pi) half-angle
        // U = V_i @ RY(f):  RY real [[cf,-sf],[sf,cf]]
        c2 U00 = {  V[i][0].x*cf + V[i][1].x*sf,  V[i][0].y*cf + V[i][1].y*sf };
        c2 U01 = { -V[i][0].x*sf + V[i][1].x*cf, -V[i][0].y*sf + V[i][1].y*cf };
        c2 U10 = {  V[i][2].x*cf + V[i][3].x*sf,  V[i][2].y*cf + V[i][3].y*sf };
        c2 U11 = { -V[i][2].x*sf + V[i][3].x*cf, -V[i][2].y*sf + V[i][3].y*cf };

        const int m = 8 >> i;   // qubit i = bit (3-i) of flat index
        #pragma unroll
        for (int k = 0; k < 16; ++k) {
            if (k & m) continue;
            const c2 a0 = { ar[k],     ai[k]     };
            const c2 a1 = { ar[k | m], ai[k | m] };
            ar[k]     = U00.x*a0.x - U00.y*a0.y + U01.x*a1.x - U01.y*a1.y;
            ai[k]     = U00.x*a0.y + U00.y*a0.x + U01.x*a1.y + U01.y*a1.x;
            ar[k | m] = U10.x*a0.x - U10.y*a0.y + U11.x*a1.x - U11.y*a1.y;
            ai[k | m] = U10.x*a0.y + U10.y*a0.x + U11.x*a1.y + U11.y*a1.x;
        }
    }

    // CNOT ring (0,1),(1,2),(2,3),(3,0): register permutation
    const int cn[4][2] = { {8,4}, {4,2}, {2,1}, {1,8} };  // {ctrl_mask, tgt_mask}
    #pragma unroll
    for (int g = 0; g < 4; ++g) {
        const int mc = cn[g][0], mt = cn[g][1];
        #pragma unroll
        for (int k = 0; k < 16; ++k) {
            if ((k & mc) && !(k & mt)) {
                float tr = ar[k]; ar[k] = ar[k | mt]; ar[k | mt] = tr;
                float ti = ai[k]; ai[k] = ai[k | mt]; ai[k | mt] = ti;
            }
        }
    }

    // Z expectations (k compile-time -> sign folds to add/sub)
    float z[4] = {0.f, 0.f, 0.f, 0.f};
    #pragma unroll
    for (int k = 0; k < 16; ++k) {
        const float p = ar[k]*ar[k] + ai[k]*ai[k];
        #pragma unroll
        for (int i = 0; i < 4; ++i)
            z[i] += (k & (8 >> i)) ? -p : p;
    }

    // mean over reuse pair (adjacent lanes), head, store
    float zm[4];
    #pragma unroll
    for (int i = 0; i < 4; ++i)
        zm[i] = 0.5f * (z[i] + __shfl_xor(z[i], 1, 64));

    const int orow = base + (lane >> 1);
    if (u == 0 && orow < B) {
        float o0 = bc[0], o1 = bc[1];
        #pragma unroll
        for (int i = 0; i < 4; ++i) {
            o0 += Wc[i]     * zm[i];
            o1 += Wc[4 + i] * zm[i];
        }
        ((float2*)out)[orow] = make_float2(o0, o1);
    }
}

// =====================================================================
extern "C" void kernel_launch(void* const* d_in, const int* in_sizes, int n_in,
                              void* d_out, int out_size, void* d_ws, size_t ws_size,
                              hipStream_t stream)
{
    const float* x     = (const float*)d_in[0];   // [B][512]
    const float* W_ctq = (const float*)d_in[1];   // [8][512]
    const float* b_ctq = (const float*)d_in[2];   // [8]
    const float* qp    = (const float*)d_in[3];   // [12]
    const float* W_cls = (const float*)d_in[4];   // [2][4]
    const float* b_cls = (const float*)d_in[5];   // [2]
    float* out = (float*)d_out;

    const int D = in_sizes[1] / 8;        // 512
    const int B = in_sizes[0] / D;        // 65536

    const int nwaves = (B + ROWS_PER_WAVE - 1) / ROWS_PER_WAVE;  // 2048
    const int blocks = (nwaves + 3) / 4;                          // 512

    bqc_fused_kernel<<<blocks, 256, 0, stream>>>(x, W_ctq, b_ctq, qp, W_cls, b_cls, out, B);
}

// Round 4
// 200.724 us; speedup vs baseline: 1.0013x; 1.0013x over previous
//
#include <hip/hip_runtime.h>
#include <math.h>

#define D_IN 512          // feature dim
#define ROWS_PER_WAVE 32  // rows per wave = 64 lanes / 2 reuse samples

// ---------- complex helpers ----------
struct c2 { float x, y; };
__device__ __forceinline__ c2 cmul(c2 a, c2 b) { return {a.x*b.x - a.y*b.y, a.x*b.y + a.y*b.x}; }

// Packed butterfly merge: lanes with (lane&o)==0 end with (a + a_partner),
// lanes with (lane&o)!=0 end with (b + b_partner).
#define PACK2(dst, aa, bb, o)                                   \
    {                                                           \
        float v_ = (lane & (o)) ? (bb) : (aa);                  \
        float u_ = (lane & (o)) ? (aa) : (bb);                  \
        dst = v_ + __shfl_xor(u_, (o), 64);                     \
    }

// =====================================================================
// Fully fused: GEMV8 (wave-per-row) + 4-qubit circuit + reuse-mean + head.
// Wave w owns rows [32w, 32w+32). Rows processed 2 at a time with depth-2
// prefetch; the two reduction chains interleave to hide DS latency.
// After the row loop, lane 2r+u holds the 4 features of sample
// (row 32w+r, reuse u); all 64 lanes then run one circuit each.
// =====================================================================
__global__ __launch_bounds__(256, 2)
void bqc_fused_kernel(const float* __restrict__ x,     // [B][512]
                      const float* __restrict__ W,     // [8][512]
                      const float* __restrict__ bias,  // [8]
                      const float* __restrict__ qp,    // [12]
                      const float* __restrict__ Wc,    // [2][4]
                      const float* __restrict__ bc,    // [2]
                      float* __restrict__ out,         // [B][2]
                      int B)
{
    const int lane = threadIdx.x & 63;
    const int wid  = blockIdx.x * (blockDim.x >> 6) + (threadIdx.x >> 6);
    const int base = wid * ROWS_PER_WAVE;
    if (base >= B) return;

    // ---- register-resident W slice: W[j][8*lane .. 8*lane+8) ----
    float4 w0[8], w1[8];
    #pragma unroll
    for (int j = 0; j < 8; ++j) {
        const float4* wp = (const float4*)(W + j * D_IN + lane * 8);
        w0[j] = wp[0]; w1[j] = wp[1];
    }

    const int u = lane & 1;                       // reuse index of this lane
    const int gbase = (lane & 56) | (u << 2);     // shfl source base

    float f[4] = {0.f, 0.f, 0.f, 0.f};            // this lane's sample features

    const float* xl = x + lane * 8;

    // prime: rows base, base+1
    float4 ca0, ca1, cb0, cb1;
    {
        const float4* pa = (const float4*)(xl + (size_t)base * D_IN);
        const float4* pb = (const float4*)(xl + (size_t)(base + 1) * D_IN);
        ca0 = pa[0]; ca1 = pa[1];
        cb0 = pb[0]; cb1 = pb[1];
    }

    for (int rr = 0; rr < ROWS_PER_WAVE; rr += 2) {
        // depth-2 prefetch: rows rr+2, rr+3 (clamped)
        const int ra = min(base + rr + 2, B - 1);
        const int rb = min(base + rr + 3, B - 1);
        const float4* pa = (const float4*)(xl + (size_t)ra * D_IN);
        const float4* pb = (const float4*)(xl + (size_t)rb * D_IN);
        float4 na0 = pa[0], na1 = pa[1];
        float4 nb0 = pb[0], nb1 = pb[1];

        float accA[8], accB[8];
        #pragma unroll
        for (int j = 0; j < 8; ++j) {
            accA[j] = ca0.x*w0[j].x + ca0.y*w0[j].y + ca0.z*w0[j].z + ca0.w*w0[j].w
                    + ca1.x*w1[j].x + ca1.y*w1[j].y + ca1.z*w1[j].z + ca1.w*w1[j].w;
            accB[j] = cb0.x*w0[j].x + cb0.y*w0[j].y + cb0.z*w0[j].z + cb0.w*w0[j].w
                    + cb1.x*w1[j].x + cb1.y*w1[j].y + cb1.z*w1[j].z + cb1.w*w1[j].w;
        }

        // interleaved packed reductions (two independent chains)
        float Ap0, Ap1, Ap2, Ap3, Bp0, Bp1, Bp2, Bp3;
        PACK2(Ap0, accA[0], accA[1], 1);  PACK2(Bp0, accB[0], accB[1], 1);
        PACK2(Ap1, accA[2], accA[3], 1);  PACK2(Bp1, accB[2], accB[3], 1);
        PACK2(Ap2, accA[4], accA[5], 1);  PACK2(Bp2, accB[4], accB[5], 1);
        PACK2(Ap3, accA[6], accA[7], 1);  PACK2(Bp3, accB[6], accB[7], 1);
        float Aq0, Aq1, Bq0, Bq1;
        PACK2(Aq0, Ap0, Ap1, 2);          PACK2(Bq0, Bp0, Bp1, 2);
        PACK2(Aq1, Ap2, Ap3, 2);          PACK2(Bq1, Bp2, Bp3, 2);
        float rA, rB;
        PACK2(rA, Aq0, Aq1, 4);           PACK2(rB, Bq0, Bq1, 4);
        rA += __shfl_xor(rA,  8, 64);     rB += __shfl_xor(rB,  8, 64);
        rA += __shfl_xor(rA, 16, 64);     rB += __shfl_xor(rB, 16, 64);
        rA += __shfl_xor(rA, 32, 64);     rB += __shfl_xor(rB, 32, 64);
        // lane l now holds full dot S_{l&7} for its row

        // deposit features: row rr -> lane pair (2rr, 2rr+1), row rr+1 likewise
        float gA0 = __shfl(rA, gbase + 0, 64);
        float gA1 = __shfl(rA, gbase + 1, 64);
        float gA2 = __shfl(rA, gbase + 2, 64);
        float gA3 = __shfl(rA, gbase + 3, 64);
        float gB0 = __shfl(rB, gbase + 0, 64);
        float gB1 = __shfl(rB, gbase + 1, 64);
        float gB2 = __shfl(rB, gbase + 2, 64);
        float gB3 = __shfl(rB, gbase + 3, 64);
        const bool mineA = ((lane >> 1) == rr);
        const bool mineB = ((lane >> 1) == rr + 1);
        f[0] = mineA ? gA0 : (mineB ? gB0 : f[0]);
        f[1] = mineA ? gA1 : (mineB ? gB1 : f[1]);
        f[2] = mineA ? gA2 : (mineB ? gB2 : f[2]);
        f[3] = mineA ? gA3 : (mineB ? gB3 : f[3]);

        ca0 = na0; ca1 = na1; cb0 = nb0; cb1 = nb1;
    }

    // bias for this lane's reuse half
    #pragma unroll
    for (int j = 0; j < 4; ++j) f[j] += bias[4*u + j];

    // ---- trainable unitaries V_i = RZ(c) RY(b) RX(a) (composed here, after
    //      the row loop, to keep VGPR pressure low during streaming) ----
    c2 V[4][4];
    #pragma unroll
    for (int i = 0; i < 4; ++i) {
        float sa, ca, sb, cb, sc, cc;
        __sincosf(qp[3*i]   * 0.5f, &sa, &ca);   // RX half-angle
        __sincosf(qp[3*i+1] * 0.5f, &sb, &cb);   // RY half-angle
        __sincosf(qp[3*i+2] * 0.5f, &sc, &cc);   // RZ half-angle
        // M = RY(b) @ RX(a)
        c2 M00 = {  cb*ca,  sb*sa };
        c2 M01 = { -sb*ca, -cb*sa };
        c2 M10 = {  sb*ca, -cb*sa };
        c2 M11 = {  cb*ca, -sb*sa };
        // V = diag(e^{-ic/2}, e^{+ic/2}) @ M
        c2 e0 = { cc, -sc }, e1 = { cc, sc };
        V[i][0] = cmul(e0, M00); V[i][1] = cmul(e0, M01);
        V[i][2] = cmul(e1, M10); V[i][3] = cmul(e1, M11);
    }

    // ---- 4-qubit circuit, one sample per lane ----
    float ar[16], ai[16];
    #pragma unroll
    for (int k = 0; k < 16; ++k) { ar[k] = 0.25f; ai[k] = 0.f; }  // H^4 |0000>

    #pragma unroll
    for (int i = 0; i < 4; ++i) {
        float sf, cf;
        __sincosf(f[i] * 1.57079632679489662f, &sf, &cf);  // RY(feat*pi) half-angle
        // U = V_i @ RY(f)
        c2 U00 = {  V[i][0].x*cf + V[i][1].x*sf,  V[i][0].y*cf + V[i][1].y*sf };
        c2 U01 = { -V[i][0].x*sf + V[i][1].x*cf, -V[i][0].y*sf + V[i][1].y*cf };
        c2 U10 = {  V[i][2].x*cf + V[i][3].x*sf,  V[i][2].y*cf + V[i][3].y*sf };
        c2 U11 = { -V[i][2].x*sf + V[i][3].x*cf, -V[i][2].y*sf + V[i][3].y*cf };

        const int m = 8 >> i;   // qubit i = bit (3-i) of flat index
        #pragma unroll
        for (int k = 0; k < 16; ++k) {
            if (k & m) continue;
            const c2 a0 = { ar[k],     ai[k]     };
            const c2 a1 = { ar[k | m], ai[k | m] };
            ar[k]     = U00.x*a0.x - U00.y*a0.y + U01.x*a1.x - U01.y*a1.y;
            ai[k]     = U00.x*a0.y + U00.y*a0.x + U01.x*a1.y + U01.y*a1.x;
            ar[k | m] = U10.x*a0.x - U10.y*a0.y + U11.x*a1.x - U11.y*a1.y;
            ai[k | m] = U10.x*a0.y + U10.y*a0.x + U11.x*a1.y + U11.y*a1.x;
        }
    }

    // CNOT ring (0,1),(1,2),(2,3),(3,0): register permutation
    const int cn[4][2] = { {8,4}, {4,2}, {2,1}, {1,8} };  // {ctrl_mask, tgt_mask}
    #pragma unroll
    for (int g = 0; g < 4; ++g) {
        const int mc = cn[g][0], mt = cn[g][1];
        #pragma unroll
        for (int k = 0; k < 16; ++k) {
            if ((k & mc) && !(k & mt)) {
                float tr = ar[k]; ar[k] = ar[k | mt]; ar[k | mt] = tr;
                float ti = ai[k]; ai[k] = ai[k | mt]; ai[k | mt] = ti;
            }
        }
    }

    // Z expectations
    float z[4] = {0.f, 0.f, 0.f, 0.f};
    #pragma unroll
    for (int k = 0; k < 16; ++k) {
        const float p = ar[k]*ar[k] + ai[k]*ai[k];
        #pragma unroll
        for (int i = 0; i < 4; ++i)
            z[i] += (k & (8 >> i)) ? -p : p;
    }

    // mean over reuse pair (adjacent lanes), head, store
    float zm[4];
    #pragma unroll
    for (int i = 0; i < 4; ++i)
        zm[i] = 0.5f * (z[i] + __shfl_xor(z[i], 1, 64));

    const int orow = base + (lane >> 1);
    if (u == 0 && orow < B) {
        float o0 = bc[0], o1 = bc[1];
        #pragma unroll
        for (int i = 0; i < 4; ++i) {
            o0 += Wc[i]     * zm[i];
            o1 += Wc[4 + i] * zm[i];
        }
        ((float2*)out)[orow] = make_float2(o0, o1);
    }
}

// =====================================================================
extern "C" void kernel_launch(void* const* d_in, const int* in_sizes, int n_in,
                              void* d_out, int out_size, void* d_ws, size_t ws_size,
                              hipStream_t stream)
{
    const float* x     = (const float*)d_in[0];   // [B][512]
    const float* W_ctq = (const float*)d_in[1];   // [8][512]
    const float* b_ctq = (const float*)d_in[2];   // [8]
    const float* qp    = (const float*)d_in[3];   // [12]
    const float* W_cls = (const float*)d_in[4];   // [2][4]
    const float* b_cls = (const float*)d_in[5];   // [2]
    float* out = (float*)d_out;

    const int D = in_sizes[1] / 8;        // 512
    const int B = in_sizes[0] / D;        // 65536

    const int nwaves = (B + ROWS_PER_WAVE - 1) / ROWS_PER_WAVE;  // 2048
    const int blocks = (nwaves + 3) / 4;                          // 512

    bqc_fused_kernel<<<blocks, 256, 0, stream>>>(x, W_ctq, b_ctq, qp, W_cls, b_cls, out, B);
}